// Round 9
// baseline (2195.540 us; speedup 1.0000x reference)
//
#include <hip/hip_runtime.h>
#include <math.h>

#define L_ 6
#define H_ 6
#define HS_ 64
#define D_ 384
#define T_ 256
#define V_ 65
#define B_ 64
#define ROWS (B_*T_)        // 16384
#define QKVN 1152
#define EPS_ 1e-5f

typedef __attribute__((ext_vector_type(8))) __bf16 bf16x8;
typedef __attribute__((ext_vector_type(4))) float f32x4;

__device__ __forceinline__ bf16x8 u4_to_bf8(uint4 u) {
    return __builtin_bit_cast(bf16x8, u);
}

// async global->LDS, 16B per lane. lds ptr wave-uniform; HW scatters lane i to lds + i*16.
__device__ __forceinline__ void glds16(const void* g, void* l) {
    __builtin_amdgcn_global_load_lds(
        (const __attribute__((address_space(1))) void*)g,
        (__attribute__((address_space(3))) void*)l, 16, 0, 0);
}

// ---------------------------------------------------------------- embedding
__global__ void embed_kernel(const int* __restrict__ idx,
                             const float* __restrict__ tok,
                             const float* __restrict__ pos,
                             float* __restrict__ x) {
    int i = blockIdx.x * blockDim.x + threadIdx.x;   // < ROWS*D_
    int d = i % D_;
    int row = i / D_;
    int t = row % T_;
    x[i] = tok[idx[row]*D_ + d] + pos[t*D_ + d];
}

// ---------------------------------------------------------------- layernorm
// wave per row, 4 rows per 256-thread block. bf16 out.
__global__ __launch_bounds__(256)
void ln4(const float* __restrict__ x,
         const float* __restrict__ g,
         const float* __restrict__ b,
         __bf16* __restrict__ yb) {
    int w = threadIdx.x >> 6, lane = threadIdx.x & 63;
    int row = blockIdx.x * 4 + w;
    const float* xr = x + (size_t)row * D_;
    float v[6];
    #pragma unroll
    for (int i = 0; i < 6; ++i) v[i] = xr[lane + 64*i];
    float s = 0.f, sq = 0.f;
    #pragma unroll
    for (int i = 0; i < 6; ++i) { s += v[i]; sq += v[i]*v[i]; }
    for (int off = 32; off; off >>= 1) {
        s  += __shfl_xor(s,  off);
        sq += __shfl_xor(sq, off);
    }
    float mean = s * (1.0f/D_);
    float var  = sq * (1.0f/D_) - mean*mean;
    float rstd = rsqrtf(var + EPS_);
    __bf16* yr = yb + (size_t)row * D_;
    #pragma unroll
    for (int i = 0; i < 6; ++i) {
        int c = lane + 64*i;
        yr[c] = (__bf16)((v[i]-mean)*rstd*g[c] + b[c]);
    }
}

// ---------------------------------------------------------------- transpose+cast (w2 only)
__global__ __launch_bounds__(256)
void transpose_cast(const float* __restrict__ src, __bf16* __restrict__ dst,
                    int R, int C, int zdiv, long sA, long sB, long dbase)
{
    __shared__ float tile[32][33];
    int z = blockIdx.z;
    const float* s = src + (long)z * R * C;
    __bf16* d = dst + dbase + (long)(z / zdiv) * sA + (long)(z % zdiv) * sB;
    int c0 = blockIdx.x * 32, r0 = blockIdx.y * 32;
    int t = threadIdx.x;
    int tr = t >> 3, tc = (t & 7) * 4;
    float4 v = *(const float4*)(s + (long)(r0 + tr) * C + c0 + tc);
    tile[tr][tc+0] = v.x; tile[tr][tc+1] = v.y;
    tile[tr][tc+2] = v.z; tile[tr][tc+3] = v.w;
    __syncthreads();
    #pragma unroll
    for (int j = 0; j < 4; ++j)
        d[(long)(c0 + tr) * R + r0 + tc + j] = (__bf16)tile[tc+j][tr];
}

// ---------------------------------------------------------------- weight pack (fragment-major)
// packed uint4 index = ((nc*KC + kc)*4 + j)*64 + lane; holds W[k][n] for
// n = nc*64 + j*16 + (lane&15), k = kc*32 + (lane>>4)*8 + e, e=0..7.
// src element (k,n) at src[(n/hb)*hstride + k*kstride + (n%hb)]; n>=nlim -> 0.
__global__ __launch_bounds__(256)
void wpack(const float* __restrict__ src, __bf16* __restrict__ dst,
           int KC, int hb, long hstride, int kstride, int nlim,
           long srcStride, long dstStride)
{
    src += (long)blockIdx.y * srcStride;
    dst += (long)blockIdx.y * dstStride;
    int t = blockIdx.x * 256 + threadIdx.x;
    int lane = t & 63, ln = lane & 15, quad = lane >> 4;
    int t2 = t >> 6;
    int j = t2 & 3;
    int t3 = t2 >> 2;
    int kc = t3 % KC, nc = t3 / KC;
    int n = nc*64 + j*16 + ln;
    int k0 = kc*32 + quad*8;
    __bf16 v8[8];
    if (n < nlim) {
        const float* sp = src + (long)(n / hb) * hstride + (n % hb);
        #pragma unroll
        for (int e = 0; e < 8; ++e)
            v8[e] = (__bf16)sp[(long)(k0 + e) * kstride];
    } else {
        #pragma unroll
        for (int e = 0; e < 8; ++e) v8[e] = (__bf16)0.0f;
    }
    *(uint4*)(dst + (size_t)t * 8) = *(const uint4*)v8;
}

// ---------------------------------------------------------------- fragment-streaming GEMM (K=384)
// A[64-row strip][384] staged once in LDS (stride 392); ONE barrier total.
// grid = (M/64, NS): slice y's wave w sweeps chunks y*4+w, +4*NS, ...
// B frags streamed from PACKED layout (coalesced 1-KB loads, 3-deep prefetch).
// C = act(A @ W + bias) (+res).
__global__ __launch_bounds__(256)
void gemm_fs(const __bf16* __restrict__ A, const __bf16* __restrict__ Bp,
             const float* __restrict__ bias, const float* res,
             float* outF, __bf16* outB,
             int N, int ldc, int ncols, int relu)
{
    __shared__ __align__(16) __bf16 As[64*392];
    int t = threadIdx.x;
    int w = t >> 6, lane = t & 63;
    int ln = lane & 15, quad = lane >> 4;
    int m0 = blockIdx.x * 64;
    int ns = gridDim.y;
    int nstep = 4 * ns;

    // stage A strip: 64 rows x 48 uint4 chunks each
    for (int c = t; c < 3072; c += 256) {
        int r = c / 48, ch = c - r*48;
        uint4 v = *(const uint4*)(A + (size_t)(m0 + r)*384 + ch*8);
        *(uint4*)&As[r*392 + ch*8] = v;
    }
    __syncthreads();        // the only barrier

    int nch = N >> 6;
    for (int nc = blockIdx.y*4 + w; nc < nch; nc += nstep) {
        int n0 = nc * 64;
        const uint4* bp = (const uint4*)Bp + (size_t)nc * 3072 + lane;
        f32x4 acc[4][4] = {};
        uint4 bb[3][4];
        #pragma unroll
        for (int s = 0; s < 3; ++s)
            #pragma unroll
            for (int j = 0; j < 4; ++j)
                bb[s][j] = bp[(s*4 + j)*64];
        #pragma unroll
        for (int kc = 0; kc < 12; ++kc) {
            int sl = kc % 3;
            uint4 af[4];
            #pragma unroll
            for (int i = 0; i < 4; ++i)
                af[i] = *(const uint4*)&As[(i*16 + ln)*392 + kc*32 + quad*8];
            #pragma unroll
            for (int i = 0; i < 4; ++i)
                #pragma unroll
                for (int j = 0; j < 4; ++j)
                    acc[i][j] = __builtin_amdgcn_mfma_f32_16x16x32_bf16(
                        __builtin_bit_cast(bf16x8, af[i]),
                        __builtin_bit_cast(bf16x8, bb[sl][j]), acc[i][j], 0, 0, 0);
            if (kc + 3 < 12) {
                #pragma unroll
                for (int j = 0; j < 4; ++j)
                    bb[sl][j] = bp[((kc+3)*4 + j)*64];
            }
        }
        // epilogue
        #pragma unroll
        for (int i = 0; i < 4; ++i) {
            #pragma unroll
            for (int r = 0; r < 4; ++r) {
                int row = m0 + i*16 + quad*4 + r;
                #pragma unroll
                for (int j = 0; j < 4; ++j) {
                    int col = n0 + j*16 + ln;
                    if (col < ncols) {
                        float v = acc[i][j][r];
                        if (bias) v += bias[col];
                        if (relu) v = fmaxf(v, 0.f);
                        if (res)  v += res[(size_t)row*ldc + col];
                        if (outF) outF[(size_t)row*ldc + col] = v;
                        if (outB) outB[(size_t)row*ldc + col] = (__bf16)v;
                    }
                }
            }
        }
    }
}

// ---------------------------------------------------------------- bf16 MFMA GEMM (ffn2: K=1536)
// double-buffered LDS, XOR chunk swizzle, TM x 128 tile, BK=32, 256 thr = 4 waves.
template<int TM>
__global__ __launch_bounds__(256)
void gemm_t(const __bf16* __restrict__ A, const __bf16* __restrict__ Bt,
            const float* __restrict__ bias, const float* res,
            float* outF, __bf16* outB,
            int K, int ldc, int ncols, int relu)
{
    constexpr int MI = TM / 32;              // mfma row-tiles per wave
    __shared__ __align__(16) __bf16 As[2][TM*32];
    __shared__ __align__(16) __bf16 Bs[2][128*32];
    int t = threadIdx.x;
    int w = t >> 6, lane = t & 63;
    int ln = lane & 15, quad = lane >> 4;
    int n0 = blockIdx.x * 128, m0 = blockIdx.y * TM;
    int wm = (w >> 1) * (TM/2), wn = (w & 1) * 64;

    f32x4 acc[MI][4] = {};

    const char* Ab = (const char*)A + (size_t)m0 * K * 2;
    const char* Bb = (const char*)Bt + (size_t)n0 * K * 2;
    int f0 = w*64 + lane, f1 = f0 + 256;
    int r0 = f0 >> 2, r1 = f1 >> 2;
    size_t ga0 = (size_t)r0 * K * 2 + (size_t)(((f0 & 3) ^ (r0 & 3)) * 16);
    size_t ga1 = (size_t)r1 * K * 2 + (size_t)(((f1 & 3) ^ (r1 & 3)) * 16);
    int lo0 = w*64*16, lo1 = (w*64 + 256)*16;

    int nIt = K >> 5;
    glds16(Ab + ga0, (char*)As[0] + lo0);
    if constexpr (TM == 128) glds16(Ab + ga1, (char*)As[0] + lo1);
    glds16(Bb + ga0, (char*)Bs[0] + lo0);
    glds16(Bb + ga1, (char*)Bs[0] + lo1);

    for (int it = 0; it < nIt; ++it) {
        int p = it & 1;
        __syncthreads();
        if (it + 1 < nIt) {
            size_t kb = (size_t)(it + 1) * 64;
            glds16(Ab + ga0 + kb, (char*)As[p^1] + lo0);
            if constexpr (TM == 128) glds16(Ab + ga1 + kb, (char*)As[p^1] + lo1);
            glds16(Bb + ga0 + kb, (char*)Bs[p^1] + lo0);
            glds16(Bb + ga1 + kb, (char*)Bs[p^1] + lo1);
        }
        bf16x8 af[MI], bfr[4];
        #pragma unroll
        for (int i = 0; i < MI; ++i) {
            int row = wm + i*16 + ln;
            af[i] = __builtin_bit_cast(bf16x8,
                *(const uint4*)&As[p][row*32 + ((quad ^ (row & 3)) * 8)]);
        }
        #pragma unroll
        for (int j = 0; j < 4; ++j) {
            int row = wn + j*16 + ln;
            bfr[j] = __builtin_bit_cast(bf16x8,
                *(const uint4*)&Bs[p][row*32 + ((quad ^ (row & 3)) * 8)]);
        }
        #pragma unroll
        for (int i = 0; i < MI; ++i)
            #pragma unroll
            for (int j = 0; j < 4; ++j)
                acc[i][j] = __builtin_amdgcn_mfma_f32_16x16x32_bf16(
                                af[i], bfr[j], acc[i][j], 0, 0, 0);
        __syncthreads();
    }
    #pragma unroll
    for (int i = 0; i < MI; ++i) {
        #pragma unroll
        for (int r = 0; r < 4; ++r) {
            int row = m0 + wm + i*16 + quad*4 + r;
            #pragma unroll
            for (int j = 0; j < 4; ++j) {
                int col = n0 + wn + j*16 + ln;
                if (col < ncols) {
                    float v = acc[i][j][r];
                    if (bias) v += bias[col];
                    if (relu) v = fmaxf(v, 0.f);
                    if (res)  v += res[(size_t)row*ldc + col];
                    if (outF) outF[(size_t)row*ldc + col] = v;
                    if (outB) outB[(size_t)row*ldc + col] = (__bf16)v;
                }
            }
        }
    }
}

// ---------------------------------------------------------------- MFMA flash attention
// one block per (b,h); 32-row q-tiles; wave w owns q-tiles {w, 7-w} (9 s-subtiles each).
// K [256][72] LDS; V^T bank-swizzled [64 e][264 s]; per-wave P [32][40]. ~81KB -> 2 blocks/CU.
__global__ __launch_bounds__(256, 2)
void attn4(const __bf16* __restrict__ qkv, __bf16* __restrict__ o)
{
    __shared__ __align__(16) __bf16 Ks[256*72];
    __shared__ __align__(16) __bf16 Vt[64*264];
    __shared__ __align__(16) __bf16 Pw[4][32*40];
    int bid = blockIdx.x;
    int h = bid % H_;
    int b = bid / H_;
    int t = threadIdx.x;
    int w = t >> 6, lane = t & 63;
    int ln = lane & 15, quad = lane >> 4;
    const size_t rowb = (size_t)b * T_ * QKVN;
    const int hoff = h * HS_;
    const float scale = 0.05103103630798288f;   // 1/sqrt(384)

    // stage K rows + swizzled V^T: elem (e, s) at Vt[e*264 + ((s>>3)^((e>>3)&3))*8 + (s&7)]
    for (int c = t; c < 2048; c += 256) {
        int r = c >> 3, e0 = (c & 7) * 8;
        uint4 uk = *(const uint4*)(qkv + rowb + (size_t)r*QKVN + 384 + hoff + e0);
        *(uint4*)&Ks[r*72 + e0] = uk;
        uint4 uv = *(const uint4*)(qkv + rowb + (size_t)r*QKVN + 768 + hoff + e0);
        bf16x8 v8 = u4_to_bf8(uv);
        #pragma unroll
        for (int j = 0; j < 8; ++j) {
            int e = e0 + j;
            Vt[e*264 + (((r >> 3) ^ ((e >> 3) & 3)) * 8) + (r & 7)] = v8[j];
        }
    }

    // Q fragments for both q-tiles (A-layout: m=ln, k=quad*8+j)
    int qis[2] = { w, 7 - w };
    uint4 Qf[2][2][2];
    #pragma unroll
    for (int tl = 0; tl < 2; ++tl)
        #pragma unroll
        for (int mi = 0; mi < 2; ++mi)
            #pragma unroll
            for (int kc = 0; kc < 2; ++kc)
                Qf[tl][mi][kc] = *(const uint4*)(qkv + rowb +
                    (size_t)(qis[tl]*32 + mi*16 + ln)*QKVN + hoff + kc*32 + quad*8);

    __syncthreads();

    __bf16* P = Pw[w];
    #pragma unroll
    for (int tl = 0; tl < 2; ++tl) {
        int qi = qis[tl];
        f32x4 O[2][4] = {};
        float mst[2][4], lst[2][4];
        #pragma unroll
        for (int mi = 0; mi < 2; ++mi)
            #pragma unroll
            for (int r = 0; r < 4; ++r) { mst[mi][r] = -INFINITY; lst[mi][r] = 0.f; }

        for (int st = 0; st <= qi; ++st) {
            int sb = st * 32;
            f32x4 S[2][2] = {};
            #pragma unroll
            for (int kc = 0; kc < 2; ++kc) {
                uint4 Kf[2];
                #pragma unroll
                for (int ji = 0; ji < 2; ++ji)
                    Kf[ji] = *(const uint4*)&Ks[(sb + ji*16 + ln)*72 + kc*32 + quad*8];
                #pragma unroll
                for (int mi = 0; mi < 2; ++mi) {
                    bf16x8 qa = __builtin_bit_cast(bf16x8, Qf[tl][mi][kc]);
                    #pragma unroll
                    for (int ji = 0; ji < 2; ++ji)
                        S[mi][ji] = __builtin_amdgcn_mfma_f32_16x16x32_bf16(
                            qa, __builtin_bit_cast(bf16x8, Kf[ji]), S[mi][ji], 0, 0, 0);
                }
            }
            int diag = (st == qi);
            #pragma unroll
            for (int mi = 0; mi < 2; ++mi)
                #pragma unroll
                for (int ji = 0; ji < 2; ++ji)
                    #pragma unroll
                    for (int r = 0; r < 4; ++r) {
                        float v = S[mi][ji][r] * scale;
                        if (diag && (ji*16 + ln) > (mi*16 + quad*4 + r)) v = -INFINITY;
                        S[mi][ji][r] = v;
                    }
            // online softmax per row (cols spread over 16-lane group)
            #pragma unroll
            for (int mi = 0; mi < 2; ++mi)
                #pragma unroll
                for (int r = 0; r < 4; ++r) {
                    float mx = fmaxf(S[mi][0][r], S[mi][1][r]);
                    #pragma unroll
                    for (int off = 1; off < 16; off <<= 1)
                        mx = fmaxf(mx, __shfl_xor(mx, off));
                    float mn = fmaxf(mst[mi][r], mx);
                    float al = __expf(mst[mi][r] - mn);
                    mst[mi][r] = mn;
                    float p0 = __expf(S[mi][0][r] - mn);
                    float p1 = __expf(S[mi][1][r] - mn);
                    S[mi][0][r] = p0; S[mi][1][r] = p1;
                    float rs = p0 + p1;
                    #pragma unroll
                    for (int off = 1; off < 16; off <<= 1)
                        rs += __shfl_xor(rs, off);
                    lst[mi][r] = lst[mi][r]*al + rs;
                    #pragma unroll
                    for (int ei = 0; ei < 4; ++ei) O[mi][ei][r] *= al;
                }
            // P (C layout) -> per-wave LDS -> A layout
            #pragma unroll
            for (int mi = 0; mi < 2; ++mi)
                #pragma unroll
                for (int ji = 0; ji < 2; ++ji)
                    #pragma unroll
                    for (int r = 0; r < 4; ++r)
                        P[(mi*16 + quad*4 + r)*40 + ji*16 + ln] = (__bf16)S[mi][ji][r];
            uint4 Pf[2], Vf[4];
            #pragma unroll
            for (int mi = 0; mi < 2; ++mi)
                Pf[mi] = *(const uint4*)&P[(mi*16 + ln)*40 + quad*8];
            #pragma unroll
            for (int ei = 0; ei < 4; ++ei) {
                int e = ei*16 + ln;
                Vf[ei] = *(const uint4*)&Vt[e*264 + (((st*4 + quad) ^ ((e >> 3) & 3)) * 8)];
            }
            #pragma unroll
            for (int mi = 0; mi < 2; ++mi)
                #pragma unroll
                for (int ei = 0; ei < 4; ++ei)
                    O[mi][ei] = __builtin_amdgcn_mfma_f32_16x16x32_bf16(
                        __builtin_bit_cast(bf16x8, Pf[mi]),
                        __builtin_bit_cast(bf16x8, Vf[ei]), O[mi][ei], 0, 0, 0);
        }
        // epilogue for this q-tile
        #pragma unroll
        for (int mi = 0; mi < 2; ++mi)
            #pragma unroll
            for (int r = 0; r < 4; ++r) {
                float inv = 1.0f / lst[mi][r];
                size_t row = (size_t)(b*T_ + qi*32 + mi*16 + quad*4 + r);
                #pragma unroll
                for (int ei = 0; ei < 4; ++ei)
                    o[row*D_ + hoff + ei*16 + ln] = (__bf16)(O[mi][ei][r] * inv);
            }
    }
}

// ---------------------------------------------------------------- loss
__global__ __launch_bounds__(256)
void loss2(const float* __restrict__ logits,
           const int* __restrict__ tg,
           float* __restrict__ loss)
{
    int row = blockIdx.x * 256 + threadIdx.x;
    const float* lr = logits + (size_t)row * V_;
    float m = -INFINITY;
    for (int c = 0; c < V_; ++c) m = fmaxf(m, lr[c]);
    float s = 0.f;
    for (int c = 0; c < V_; ++c) s += __expf(lr[c] - m);
    float val = -(lr[tg[row]] - m - __logf(s)) * (1.0f/ROWS);
    for (int off = 32; off; off >>= 1) val += __shfl_xor(val, off);
    __shared__ float red[4];
    int w = threadIdx.x >> 6, lane = threadIdx.x & 63;
    if (lane == 0) red[w] = val;
    __syncthreads();
    if (threadIdx.x == 0)
        atomicAdd(loss, red[0]+red[1]+red[2]+red[3]);
}

// ---------------------------------------------------------------- launch
extern "C" void kernel_launch(void* const* d_in, const int* in_sizes, int n_in,
                              void* d_out, int out_size, void* d_ws, size_t ws_size,
                              hipStream_t stream)
{
    const int*   idx     = (const int*)  d_in[0];
    const int*   targets = (const int*)  d_in[1];
    const float* tok     = (const float*)d_in[2];
    const float* pos     = (const float*)d_in[3];
    const float* Wq      = (const float*)d_in[4];
    const float* Wk      = (const float*)d_in[5];
    const float* Wv      = (const float*)d_in[6];
    const float* Wproj   = (const float*)d_in[7];
    const float* bproj   = (const float*)d_in[8];
    const float* W1      = (const float*)d_in[9];
    const float* b1      = (const float*)d_in[10];
    const float* W2      = (const float*)d_in[11];
    const float* b2      = (const float*)d_in[12];
    const float* ln1g    = (const float*)d_in[13];
    const float* ln1b    = (const float*)d_in[14];
    const float* lnfg    = (const float*)d_in[15];
    const float* lnfb    = (const float*)d_in[16];
    const float* Whead   = (const float*)d_in[17];
    const float* bhead   = (const float*)d_in[18];

    float* logits = (float*)d_out;
    float* loss   = logits + (size_t)ROWS * V_;

    const size_t SZ = (size_t)ROWS * D_;             // 6291456
    const size_t RGELEMS = (size_t)ROWS * 4 * D_;    // 25165824 bf16 elems

    float*  x   = (float*)d_ws;                      // SZ f32
    __bf16* yb  = (__bf16*)(x + SZ);                 // SZ bf16
    __bf16* Rg  = yb + SZ;                           // RGELEMS bf16 (qkv / hid)
    __bf16* qkv = Rg;                                // ROWS*1152
    __bf16* hid = Rg;                                // ROWS*1536
    __bf16* o   = Rg + RGELEMS;                      // SZ bf16
    __bf16* qkvP  = o + SZ;                          // L*1152*384 (packed)
    __bf16* projP = qkvP + (size_t)L_*QKVN*D_;       // L*384*384  (packed)
    __bf16* w1P   = projP + (size_t)L_*D_*D_;        // L*1536*384 (packed)
    __bf16* w2T   = w1P + (size_t)L_*D_*4*D_;        // L*384*1536 ([N][K])
    __bf16* headP = w2T + (size_t)L_*D_*4*D_;        // 128*384    (packed)

    // ---- weight prep
    // qkv packed: n-chunks 0-5 = q, 6-11 = k, 12-17 = v (contiguous thirds)
    wpack<<<dim3(72, L_), 256, 0, stream>>>(Wq, qkvP, 12, 64, (long)D_*HS_, 64,
        384, (long)H_*D_*HS_, (long)QKVN*D_);
    wpack<<<dim3(72, L_), 256, 0, stream>>>(Wk, qkvP + (size_t)D_*D_, 12, 64,
        (long)D_*HS_, 64, 384, (long)H_*D_*HS_, (long)QKVN*D_);
    wpack<<<dim3(72, L_), 256, 0, stream>>>(Wv, qkvP + 2*(size_t)D_*D_, 12, 64,
        (long)D_*HS_, 64, 384, (long)H_*D_*HS_, (long)QKVN*D_);
    wpack<<<dim3(72, L_), 256, 0, stream>>>(Wproj, projP, 12, 1<<30, 0, D_,
        384, (long)D_*D_, (long)D_*D_);
    wpack<<<dim3(288, L_), 256, 0, stream>>>(W1, w1P, 12, 1<<30, 0, 4*D_,
        1536, (long)D_*4*D_, (long)4*D_*D_);
    wpack<<<dim3(24, 1), 256, 0, stream>>>(Whead, headP, 12, 1<<30, 0, V_,
        V_, 0, 0);
    transpose_cast<<<dim3(12,48,6),256,0,stream>>>(W2, w2T, 4*D_, D_, 1,
        (long)D_*4*D_, 0L, 0L);

    embed_kernel<<<(ROWS*D_)/256, 256, 0, stream>>>(idx, tok, pos, x);

    for (int l = 0; l < L_; ++l) {
        ln4<<<ROWS/4, 256, 0, stream>>>(x, ln1g + l*D_, ln1b + l*D_, yb);
        gemm_fs<<<dim3(ROWS/64, 2), 256, 0, stream>>>(
            yb, qkvP + (size_t)l*QKVN*D_, nullptr, nullptr, nullptr, qkv,
            QKVN, QKVN, QKVN, 0);
        attn4<<<B_*H_, 256, 0, stream>>>(qkv, o);
        gemm_fs<<<dim3(ROWS/64, 2), 256, 0, stream>>>(
            o, projP + (size_t)l*D_*D_, bproj + l*D_, x, x, nullptr,
            D_, D_, D_, 0);
        ln4<<<ROWS/4, 256, 0, stream>>>(x, ln1g + l*D_, ln1b + l*D_, yb);
        gemm_fs<<<dim3(ROWS/64, 3), 256, 0, stream>>>(
            yb, w1P + (size_t)l*D_*4*D_, b1 + l*4*D_, nullptr, nullptr, hid,
            4*D_, 4*D_, 4*D_, 1);
        gemm_t<64><<<dim3(D_/128, ROWS/64), 256, 0, stream>>>(
            hid, w2T + (size_t)l*D_*4*D_, b2 + l*D_, x, x, nullptr,
            4*D_, D_, D_, 0);
    }
    ln4<<<ROWS/4, 256, 0, stream>>>(x, lnfg, lnfb, yb);
    gemm_fs<<<dim3(ROWS/64, 1), 256, 0, stream>>>(
        yb, headP, bhead, nullptr, logits, nullptr,
        128, V_, V_, 0);
    hipMemsetAsync(loss, 0, sizeof(float), stream);
    loss2<<<ROWS/256, 256, 0, stream>>>(logits, targets, loss);
}

// Round 10
// 1610.094 us; speedup vs baseline: 1.3636x; 1.3636x over previous
//
#include <hip/hip_runtime.h>
#include <math.h>

#define L_ 6
#define H_ 6
#define HS_ 64
#define D_ 384
#define T_ 256
#define V_ 65
#define B_ 64
#define ROWS (B_*T_)        // 16384
#define QKVN 1152
#define EPS_ 1e-5f

typedef __attribute__((ext_vector_type(8))) __bf16 bf16x8;
typedef __attribute__((ext_vector_type(4))) float f32x4;

__device__ __forceinline__ bf16x8 u4_to_bf8(uint4 u) {
    return __builtin_bit_cast(bf16x8, u);
}

// async global->LDS, 16B per lane. lds ptr wave-uniform; HW scatters lane i to lds + i*16.
__device__ __forceinline__ void glds16(const void* g, void* l) {
    __builtin_amdgcn_global_load_lds(
        (const __attribute__((address_space(1))) void*)g,
        (__attribute__((address_space(3))) void*)l, 16, 0, 0);
}

// ---------------------------------------------------------------- embedding (bf16 x)
__global__ void embed_kernel(const int* __restrict__ idx,
                             const float* __restrict__ tok,
                             const float* __restrict__ pos,
                             __bf16* __restrict__ x) {
    int i = blockIdx.x * blockDim.x + threadIdx.x;   // < ROWS*D_
    int d = i % D_;
    int row = i / D_;
    int t = row % T_;
    x[i] = (__bf16)(tok[idx[row]*D_ + d] + pos[t*D_ + d]);
}

// ---------------------------------------------------------------- layernorm (bf16 in/out)
// wave per row, 4 rows per 256-thread block.
__global__ __launch_bounds__(256)
void ln4(const __bf16* __restrict__ x,
         const float* __restrict__ g,
         const float* __restrict__ b,
         __bf16* __restrict__ yb) {
    int w = threadIdx.x >> 6, lane = threadIdx.x & 63;
    int row = blockIdx.x * 4 + w;
    const unsigned* xr = (const unsigned*)(x + (size_t)row * D_);
    float v[6];
    #pragma unroll
    for (int i = 0; i < 3; ++i) {
        unsigned u = xr[lane + 64*i];
        v[2*i]   = __uint_as_float(u << 16);
        v[2*i+1] = __uint_as_float(u & 0xffff0000u);
    }
    float s = 0.f, sq = 0.f;
    #pragma unroll
    for (int i = 0; i < 6; ++i) { s += v[i]; sq += v[i]*v[i]; }
    for (int off = 32; off; off >>= 1) {
        s  += __shfl_xor(s,  off);
        sq += __shfl_xor(sq, off);
    }
    float mean = s * (1.0f/D_);
    float var  = sq * (1.0f/D_) - mean*mean;
    float rstd = rsqrtf(var + EPS_);
    unsigned* yr = (unsigned*)(yb + (size_t)row * D_);
    #pragma unroll
    for (int i = 0; i < 3; ++i) {
        int c = 2*(lane + 64*i);
        float o0 = (v[2*i]   - mean)*rstd*g[c]   + b[c];
        float o1 = (v[2*i+1] - mean)*rstd*g[c+1] + b[c+1];
        unsigned short h0 = __builtin_bit_cast(unsigned short, (__bf16)o0);
        unsigned short h1 = __builtin_bit_cast(unsigned short, (__bf16)o1);
        yr[lane + 64*i] = (unsigned)h0 | ((unsigned)h1 << 16);
    }
}

// ---------------------------------------------------------------- transpose+cast
__global__ __launch_bounds__(256)
void transpose_cast(const float* __restrict__ src, __bf16* __restrict__ dst,
                    int R, int C, int zdiv, long sA, long sB, long dbase)
{
    __shared__ float tile[32][33];
    int z = blockIdx.z;
    const float* s = src + (long)z * R * C;
    __bf16* d = dst + dbase + (long)(z / zdiv) * sA + (long)(z % zdiv) * sB;
    int c0 = blockIdx.x * 32, r0 = blockIdx.y * 32;
    int t = threadIdx.x;
    int tr = t >> 3, tc = (t & 7) * 4;
    float4 v = *(const float4*)(s + (long)(r0 + tr) * C + c0 + tc);
    tile[tr][tc+0] = v.x; tile[tr][tc+1] = v.y;
    tile[tr][tc+2] = v.z; tile[tr][tc+3] = v.w;
    __syncthreads();
    #pragma unroll
    for (int j = 0; j < 4; ++j)
        d[(long)(c0 + tr) * R + r0 + tc + j] = (__bf16)tile[tc+j][tr];
}

// head weight: Whead [384][65] fp32 -> headT [128][384] bf16 (zero-padded rows 65..127)
__global__ __launch_bounds__(256)
void head_prep(const float* __restrict__ Whead, __bf16* __restrict__ headT) {
    int i = blockIdx.x * 256 + threadIdx.x;   // < 128*384
    int n = i / D_, k = i % D_;
    headT[i] = (n < V_) ? (__bf16)Whead[k*V_ + n] : (__bf16)0.0f;
}

// ---------------------------------------------------------------- gemm_k: BK=96, single-buffer
// TM x 128 tile, 4 waves (2x2), K multiple of 96 -> K/96 iterations (4 for K=384).
// Fewer barrier drains than BK=32 dbuf (4 vs 12); LDS 48KB (TM=128) -> 3 blocks/CU.
// C = act(A[M,K] @ Bt^T + bias) (+res bf16); Bt is [N][K] bf16.
template<int TM>
__global__ __launch_bounds__(256)
void gemm_k(const __bf16* __restrict__ A, const __bf16* __restrict__ Bt,
            const float* __restrict__ bias, const __bf16* res,
            float* outF, __bf16* outB,
            int K, int ldc, int ncols, int relu)
{
    constexpr int MI = TM / 32;              // mfma row-tiles per wave
    constexpr int AST = (TM*12)/256;         // A staging steps (chunks of 16B, 12/row)
    __shared__ __align__(16) __bf16 As[TM*96];
    __shared__ __align__(16) __bf16 Bs[128*96];
    int t = threadIdx.x;
    int w = t >> 6, lane = t & 63;
    int ln = lane & 15, quad = lane >> 4;
    int n0 = blockIdx.x * 128, m0 = blockIdx.y * TM;
    int wm = (w >> 1) * (TM/2), wn = (w & 1) * 64;

    f32x4 acc[MI][4] = {};
    const char* Ab = (const char*)A + (size_t)m0 * K * 2;
    const char* Bb = (const char*)Bt + (size_t)n0 * K * 2;

    int nIt = K / 96;
    for (int it = 0; it < nIt; ++it) {
        if (it) __syncthreads();             // protect LDS from overwrite
        long kb = (long)it * 192;            // 96 elems = 192 B
        #pragma unroll
        for (int s = 0; s < AST; ++s) {
            int c = s*256 + t;
            int row = c / 12, ch = c - row*12;
            glds16(Ab + (size_t)row*K*2 + kb + ch*16,
                   (char*)As + (size_t)(s*256 + w*64)*16);
        }
        #pragma unroll
        for (int s = 0; s < 6; ++s) {
            int c = s*256 + t;
            int row = c / 12, ch = c - row*12;
            glds16(Bb + (size_t)row*K*2 + kb + ch*16,
                   (char*)Bs + (size_t)(s*256 + w*64)*16);
        }
        __syncthreads();                     // drain staging
        #pragma unroll
        for (int kk = 0; kk < 3; ++kk) {
            bf16x8 af[MI], bfr[4];
            #pragma unroll
            for (int i = 0; i < MI; ++i)
                af[i] = __builtin_bit_cast(bf16x8,
                    *(const uint4*)&As[(wm + i*16 + ln)*96 + kk*32 + quad*8]);
            #pragma unroll
            for (int j = 0; j < 4; ++j)
                bfr[j] = __builtin_bit_cast(bf16x8,
                    *(const uint4*)&Bs[(wn + j*16 + ln)*96 + kk*32 + quad*8]);
            #pragma unroll
            for (int i = 0; i < MI; ++i)
                #pragma unroll
                for (int j = 0; j < 4; ++j)
                    acc[i][j] = __builtin_amdgcn_mfma_f32_16x16x32_bf16(
                                    af[i], bfr[j], acc[i][j], 0, 0, 0);
        }
    }
    #pragma unroll
    for (int i = 0; i < MI; ++i) {
        #pragma unroll
        for (int r = 0; r < 4; ++r) {
            int row = m0 + wm + i*16 + quad*4 + r;
            #pragma unroll
            for (int j = 0; j < 4; ++j) {
                int col = n0 + wn + j*16 + ln;
                if (col < ncols) {
                    float v = acc[i][j][r];
                    if (bias) v += bias[col];
                    if (relu) v = fmaxf(v, 0.f);
                    if (res)  v += (float)res[(size_t)row*ldc + col];
                    if (outF) outF[(size_t)row*ldc + col] = v;
                    if (outB) outB[(size_t)row*ldc + col] = (__bf16)v;
                }
            }
        }
    }
}

// ---------------------------------------------------------------- gemm_t (ffn2: K=1536)
// double-buffered LDS, XOR chunk swizzle, TM x 128 tile, BK=32, 256 thr = 4 waves.
template<int TM>
__global__ __launch_bounds__(256)
void gemm_t(const __bf16* __restrict__ A, const __bf16* __restrict__ Bt,
            const float* __restrict__ bias, const __bf16* res,
            float* outF, __bf16* outB,
            int K, int ldc, int ncols, int relu)
{
    constexpr int MI = TM / 32;              // mfma row-tiles per wave
    __shared__ __align__(16) __bf16 As[2][TM*32];
    __shared__ __align__(16) __bf16 Bs[2][128*32];
    int t = threadIdx.x;
    int w = t >> 6, lane = t & 63;
    int ln = lane & 15, quad = lane >> 4;
    int n0 = blockIdx.x * 128, m0 = blockIdx.y * TM;
    int wm = (w >> 1) * (TM/2), wn = (w & 1) * 64;

    f32x4 acc[MI][4] = {};

    const char* Ab = (const char*)A + (size_t)m0 * K * 2;
    const char* Bb = (const char*)Bt + (size_t)n0 * K * 2;
    int f0 = w*64 + lane, f1 = f0 + 256;
    int r0 = f0 >> 2, r1 = f1 >> 2;
    size_t ga0 = (size_t)r0 * K * 2 + (size_t)(((f0 & 3) ^ (r0 & 3)) * 16);
    size_t ga1 = (size_t)r1 * K * 2 + (size_t)(((f1 & 3) ^ (r1 & 3)) * 16);
    int lo0 = w*64*16, lo1 = (w*64 + 256)*16;

    int nIt = K >> 5;
    glds16(Ab + ga0, (char*)As[0] + lo0);
    if constexpr (TM == 128) glds16(Ab + ga1, (char*)As[0] + lo1);
    glds16(Bb + ga0, (char*)Bs[0] + lo0);
    glds16(Bb + ga1, (char*)Bs[0] + lo1);

    for (int it = 0; it < nIt; ++it) {
        int p = it & 1;
        __syncthreads();
        if (it + 1 < nIt) {
            size_t kb = (size_t)(it + 1) * 64;
            glds16(Ab + ga0 + kb, (char*)As[p^1] + lo0);
            if constexpr (TM == 128) glds16(Ab + ga1 + kb, (char*)As[p^1] + lo1);
            glds16(Bb + ga0 + kb, (char*)Bs[p^1] + lo0);
            glds16(Bb + ga1 + kb, (char*)Bs[p^1] + lo1);
        }
        bf16x8 af[MI], bfr[4];
        #pragma unroll
        for (int i = 0; i < MI; ++i) {
            int row = wm + i*16 + ln;
            af[i] = __builtin_bit_cast(bf16x8,
                *(const uint4*)&As[p][row*32 + ((quad ^ (row & 3)) * 8)]);
        }
        #pragma unroll
        for (int j = 0; j < 4; ++j) {
            int row = wn + j*16 + ln;
            bfr[j] = __builtin_bit_cast(bf16x8,
                *(const uint4*)&Bs[p][row*32 + ((quad ^ (row & 3)) * 8)]);
        }
        #pragma unroll
        for (int i = 0; i < MI; ++i)
            #pragma unroll
            for (int j = 0; j < 4; ++j)
                acc[i][j] = __builtin_amdgcn_mfma_f32_16x16x32_bf16(
                                af[i], bfr[j], acc[i][j], 0, 0, 0);
        __syncthreads();
    }
    #pragma unroll
    for (int i = 0; i < MI; ++i) {
        #pragma unroll
        for (int r = 0; r < 4; ++r) {
            int row = m0 + wm + i*16 + quad*4 + r;
            #pragma unroll
            for (int j = 0; j < 4; ++j) {
                int col = n0 + wn + j*16 + ln;
                if (col < ncols) {
                    float v = acc[i][j][r];
                    if (bias) v += bias[col];
                    if (relu) v = fmaxf(v, 0.f);
                    if (res)  v += (float)res[(size_t)row*ldc + col];
                    if (outF) outF[(size_t)row*ldc + col] = v;
                    if (outB) outB[(size_t)row*ldc + col] = (__bf16)v;
                }
            }
        }
    }
}

// ---------------------------------------------------------------- MFMA flash attention
// one block per (b,h); 32-row q-tiles; wave w owns q-tiles {w, 7-w} (9 s-subtiles each).
// K [256][72] LDS; V^T bank-swizzled [64 e][264 s]; per-wave P [32][40]. ~81KB -> 2 blocks/CU.
__global__ __launch_bounds__(256, 2)
void attn4(const __bf16* __restrict__ qkv, __bf16* __restrict__ o)
{
    __shared__ __align__(16) __bf16 Ks[256*72];
    __shared__ __align__(16) __bf16 Vt[64*264];
    __shared__ __align__(16) __bf16 Pw[4][32*40];
    int bid = blockIdx.x;
    int h = bid % H_;
    int b = bid / H_;
    int t = threadIdx.x;
    int w = t >> 6, lane = t & 63;
    int ln = lane & 15, quad = lane >> 4;
    const size_t rowb = (size_t)b * T_ * QKVN;
    const int hoff = h * HS_;
    const float scale = 0.05103103630798288f;   // 1/sqrt(384)

    // stage K rows + swizzled V^T: elem (e, s) at Vt[e*264 + ((s>>3)^((e>>3)&3))*8 + (s&7)]
    for (int c = t; c < 2048; c += 256) {
        int r = c >> 3, e0 = (c & 7) * 8;
        uint4 uk = *(const uint4*)(qkv + rowb + (size_t)r*QKVN + 384 + hoff + e0);
        *(uint4*)&Ks[r*72 + e0] = uk;
        uint4 uv = *(const uint4*)(qkv + rowb + (size_t)r*QKVN + 768 + hoff + e0);
        bf16x8 v8 = u4_to_bf8(uv);
        #pragma unroll
        for (int j = 0; j < 8; ++j) {
            int e = e0 + j;
            Vt[e*264 + (((r >> 3) ^ ((e >> 3) & 3)) * 8) + (r & 7)] = v8[j];
        }
    }

    // Q fragments for both q-tiles (A-layout: m=ln, k=quad*8+j)
    int qis[2] = { w, 7 - w };
    uint4 Qf[2][2][2];
    #pragma unroll
    for (int tl = 0; tl < 2; ++tl)
        #pragma unroll
        for (int mi = 0; mi < 2; ++mi)
            #pragma unroll
            for (int kc = 0; kc < 2; ++kc)
                Qf[tl][mi][kc] = *(const uint4*)(qkv + rowb +
                    (size_t)(qis[tl]*32 + mi*16 + ln)*QKVN + hoff + kc*32 + quad*8);

    __syncthreads();

    __bf16* P = Pw[w];
    #pragma unroll
    for (int tl = 0; tl < 2; ++tl) {
        int qi = qis[tl];
        f32x4 O[2][4] = {};
        float mst[2][4], lst[2][4];
        #pragma unroll
        for (int mi = 0; mi < 2; ++mi)
            #pragma unroll
            for (int r = 0; r < 4; ++r) { mst[mi][r] = -INFINITY; lst[mi][r] = 0.f; }

        for (int st = 0; st <= qi; ++st) {
            int sb = st * 32;
            f32x4 S[2][2] = {};
            #pragma unroll
            for (int kc = 0; kc < 2; ++kc) {
                uint4 Kf[2];
                #pragma unroll
                for (int ji = 0; ji < 2; ++ji)
                    Kf[ji] = *(const uint4*)&Ks[(sb + ji*16 + ln)*72 + kc*32 + quad*8];
                #pragma unroll
                for (int mi = 0; mi < 2; ++mi) {
                    bf16x8 qa = __builtin_bit_cast(bf16x8, Qf[tl][mi][kc]);
                    #pragma unroll
                    for (int ji = 0; ji < 2; ++ji)
                        S[mi][ji] = __builtin_amdgcn_mfma_f32_16x16x32_bf16(
                            qa, __builtin_bit_cast(bf16x8, Kf[ji]), S[mi][ji], 0, 0, 0);
                }
            }
            int diag = (st == qi);
            #pragma unroll
            for (int mi = 0; mi < 2; ++mi)
                #pragma unroll
                for (int ji = 0; ji < 2; ++ji)
                    #pragma unroll
                    for (int r = 0; r < 4; ++r) {
                        float v = S[mi][ji][r] * scale;
                        if (diag && (ji*16 + ln) > (mi*16 + quad*4 + r)) v = -INFINITY;
                        S[mi][ji][r] = v;
                    }
            // online softmax per row (cols spread over 16-lane group)
            #pragma unroll
            for (int mi = 0; mi < 2; ++mi)
                #pragma unroll
                for (int r = 0; r < 4; ++r) {
                    float mx = fmaxf(S[mi][0][r], S[mi][1][r]);
                    #pragma unroll
                    for (int off = 1; off < 16; off <<= 1)
                        mx = fmaxf(mx, __shfl_xor(mx, off));
                    float mn = fmaxf(mst[mi][r], mx);
                    float al = __expf(mst[mi][r] - mn);
                    mst[mi][r] = mn;
                    float p0 = __expf(S[mi][0][r] - mn);
                    float p1 = __expf(S[mi][1][r] - mn);
                    S[mi][0][r] = p0; S[mi][1][r] = p1;
                    float rs = p0 + p1;
                    #pragma unroll
                    for (int off = 1; off < 16; off <<= 1)
                        rs += __shfl_xor(rs, off);
                    lst[mi][r] = lst[mi][r]*al + rs;
                    #pragma unroll
                    for (int ei = 0; ei < 4; ++ei) O[mi][ei][r] *= al;
                }
            // P (C layout) -> per-wave LDS -> A layout
            #pragma unroll
            for (int mi = 0; mi < 2; ++mi)
                #pragma unroll
                for (int ji = 0; ji < 2; ++ji)
                    #pragma unroll
                    for (int r = 0; r < 4; ++r)
                        P[(mi*16 + quad*4 + r)*40 + ji*16 + ln] = (__bf16)S[mi][ji][r];
            uint4 Pf[2], Vf[4];
            #pragma unroll
            for (int mi = 0; mi < 2; ++mi)
                Pf[mi] = *(const uint4*)&P[(mi*16 + ln)*40 + quad*8];
            #pragma unroll
            for (int ei = 0; ei < 4; ++ei) {
                int e = ei*16 + ln;
                Vf[ei] = *(const uint4*)&Vt[e*264 + (((st*4 + quad) ^ ((e >> 3) & 3)) * 8)];
            }
            #pragma unroll
            for (int mi = 0; mi < 2; ++mi)
                #pragma unroll
                for (int ei = 0; ei < 4; ++ei)
                    O[mi][ei] = __builtin_amdgcn_mfma_f32_16x16x32_bf16(
                        __builtin_bit_cast(bf16x8, Pf[mi]),
                        __builtin_bit_cast(bf16x8, Vf[ei]), O[mi][ei], 0, 0, 0);
        }
        // epilogue for this q-tile
        #pragma unroll
        for (int mi = 0; mi < 2; ++mi)
            #pragma unroll
            for (int r = 0; r < 4; ++r) {
                float inv = 1.0f / lst[mi][r];
                size_t row = (size_t)(b*T_ + qi*32 + mi*16 + quad*4 + r);
                #pragma unroll
                for (int ei = 0; ei < 4; ++ei)
                    o[row*D_ + hoff + ei*16 + ln] = (__bf16)(O[mi][ei][r] * inv);
            }
    }
}

// ---------------------------------------------------------------- loss
__global__ __launch_bounds__(256)
void loss2(const float* __restrict__ logits,
           const int* __restrict__ tg,
           float* __restrict__ loss)
{
    int row = blockIdx.x * 256 + threadIdx.x;
    const float* lr = logits + (size_t)row * V_;
    float m = -INFINITY;
    for (int c = 0; c < V_; ++c) m = fmaxf(m, lr[c]);
    float s = 0.f;
    for (int c = 0; c < V_; ++c) s += __expf(lr[c] - m);
    float val = -(lr[tg[row]] - m - __logf(s)) * (1.0f/ROWS);
    for (int off = 32; off; off >>= 1) val += __shfl_xor(val, off);
    __shared__ float red[4];
    int w = threadIdx.x >> 6, lane = threadIdx.x & 63;
    if (lane == 0) red[w] = val;
    __syncthreads();
    if (threadIdx.x == 0)
        atomicAdd(loss, red[0]+red[1]+red[2]+red[3]);
}

// ---------------------------------------------------------------- launch
extern "C" void kernel_launch(void* const* d_in, const int* in_sizes, int n_in,
                              void* d_out, int out_size, void* d_ws, size_t ws_size,
                              hipStream_t stream)
{
    const int*   idx     = (const int*)  d_in[0];
    const int*   targets = (const int*)  d_in[1];
    const float* tok     = (const float*)d_in[2];
    const float* pos     = (const float*)d_in[3];
    const float* Wq      = (const float*)d_in[4];
    const float* Wk      = (const float*)d_in[5];
    const float* Wv      = (const float*)d_in[6];
    const float* Wproj   = (const float*)d_in[7];
    const float* bproj   = (const float*)d_in[8];
    const float* W1      = (const float*)d_in[9];
    const float* b1      = (const float*)d_in[10];
    const float* W2      = (const float*)d_in[11];
    const float* b2      = (const float*)d_in[12];
    const float* ln1g    = (const float*)d_in[13];
    const float* ln1b    = (const float*)d_in[14];
    const float* lnfg    = (const float*)d_in[15];
    const float* lnfb    = (const float*)d_in[16];
    const float* Whead   = (const float*)d_in[17];
    const float* bhead   = (const float*)d_in[18];

    float* logits = (float*)d_out;
    float* loss   = logits + (size_t)ROWS * V_;

    const size_t SZ = (size_t)ROWS * D_;             // 6291456
    const size_t RGELEMS = (size_t)ROWS * 4 * D_;    // 25165824 bf16 elems

    __bf16* x   = (__bf16*)d_ws;                     // SZ bf16 (residual stream)
    __bf16* yb  = x + SZ;                            // SZ bf16
    __bf16* Rg  = yb + SZ;                           // RGELEMS bf16 (qkv / hid)
    __bf16* qkv = Rg;                                // ROWS*1152
    __bf16* hid = Rg;                                // ROWS*1536
    __bf16* o   = Rg + RGELEMS;                      // SZ bf16
    __bf16* qkvT  = o + SZ;                          // L*1152*384 ([N][K])
    __bf16* projT = qkvT + (size_t)L_*QKVN*D_;       // L*384*384
    __bf16* w1T   = projT + (size_t)L_*D_*D_;        // L*1536*384
    __bf16* w2T   = w1T + (size_t)L_*D_*4*D_;        // L*384*1536
    __bf16* headT = w2T + (size_t)L_*D_*4*D_;        // 128*384

    // weight conversion (transpose to [N][K] bf16)
    transpose_cast<<<dim3(2,12,36),256,0,stream>>>(Wq, qkvT, D_, HS_, H_,
        (long)QKVN*D_, (long)HS_*D_, 0L);
    transpose_cast<<<dim3(2,12,36),256,0,stream>>>(Wk, qkvT, D_, HS_, H_,
        (long)QKVN*D_, (long)HS_*D_, (long)D_*D_);
    transpose_cast<<<dim3(2,12,36),256,0,stream>>>(Wv, qkvT, D_, HS_, H_,
        (long)QKVN*D_, (long)HS_*D_, 2L*D_*D_);
    transpose_cast<<<dim3(12,12,6),256,0,stream>>>(Wproj, projT, D_, D_, 1,
        (long)D_*D_, 0L, 0L);
    transpose_cast<<<dim3(48,12,6),256,0,stream>>>(W1, w1T, D_, 4*D_, 1,
        (long)D_*4*D_, 0L, 0L);
    transpose_cast<<<dim3(12,48,6),256,0,stream>>>(W2, w2T, 4*D_, D_, 1,
        (long)D_*4*D_, 0L, 0L);
    head_prep<<<(128*D_)/256, 256, 0, stream>>>(Whead, headT);

    embed_kernel<<<(ROWS*D_)/256, 256, 0, stream>>>(idx, tok, pos, x);

    for (int l = 0; l < L_; ++l) {
        ln4<<<ROWS/4, 256, 0, stream>>>(x, ln1g + l*D_, ln1b + l*D_, yb);
        gemm_k<128><<<dim3(QKVN/128, ROWS/128), 256, 0, stream>>>(
            yb, qkvT + (size_t)l*QKVN*D_, nullptr, nullptr, nullptr, qkv,
            D_, QKVN, QKVN, 0);
        attn4<<<B_*H_, 256, 0, stream>>>(qkv, o);
        gemm_k<64><<<dim3(D_/128, ROWS/64), 256, 0, stream>>>(
            o, projT + (size_t)l*D_*D_, bproj + l*D_, x, nullptr, x,
            D_, D_, D_, 0);
        ln4<<<ROWS/4, 256, 0, stream>>>(x, ln1g + l*D_, ln1b + l*D_, yb);
        gemm_k<128><<<dim3(4*D_/128, ROWS/128), 256, 0, stream>>>(
            yb, w1T + (size_t)l*D_*4*D_, b1 + l*4*D_, nullptr, nullptr, hid,
            D_, 4*D_, 4*D_, 1);
        gemm_t<64><<<dim3(D_/128, ROWS/64), 256, 0, stream>>>(
            hid, w2T + (size_t)l*D_*4*D_, b2 + l*D_, x, nullptr, x,
            4*D_, D_, D_, 0);
    }
    ln4<<<ROWS/4, 256, 0, stream>>>(x, lnfg, lnfb, yb);
    gemm_k<64><<<dim3(1, ROWS/64), 256, 0, stream>>>(
        yb, headT, bhead, nullptr, logits, nullptr,
        D_, V_, V_, 0);
    hipMemsetAsync(loss, 0, sizeof(float), stream);
    loss2<<<ROWS/256, 256, 0, stream>>>(logits, targets, loss);
}